// Round 15
// baseline (393.275 us; speedup 1.0000x reference)
//
#include <hip/hip_runtime.h>
#include <hip/hip_fp16.h>

#define NN 100000
#define NE 1600000
#define NNP (NN + 64)  // row-padded feature buffers (last block reads past NN)

// CSR bucket sort params
#define NPB 512                          // nodes per bucket (bucket = dst>>9)
#define NBUK ((NN + NPB - 1) / NPB)      // 196
#define EPB 2048                         // edges per binA block
#define ABLK ((NE + EPB - 1) / EPB)      // 782
#define BCAP 10240                       // segment capacity (mean 8192, sd ~90)

typedef _Float16 half8 __attribute__((ext_vector_type(8)));
typedef float f32x4 __attribute__((ext_vector_type(4)));

// ---------------- bucketed CSR build (no node-grained global atomics) ----------------

__global__ __launch_bounds__(256) void bucket_init(int* __restrict__ bucket_cur) {
  int t = blockIdx.x * 256 + threadIdx.x;
  if (t < NBUK) bucket_cur[t] = t * BCAP;
}

// pass A: bin edges by dst>>9 into fixed-capacity segments; store packed (src<<9)|local
__global__ __launch_bounds__(256) void binA(const int* __restrict__ src,
                                            const int* __restrict__ dst,
                                            int* __restrict__ bucket_cur,
                                            unsigned* __restrict__ binned) {
  __shared__ int hist[NBUK];
  __shared__ int sc[256];
  __shared__ int lbase[NBUK];
  __shared__ int gbase[NBUK];
  __shared__ int lcur[NBUK];
  __shared__ uint2 stage[EPB];
  int t = threadIdx.x;
  int e0 = blockIdx.x * EPB;
  if (t < NBUK) hist[t] = 0;
  __syncthreads();
  int es[8], ed[8];
#pragma unroll
  for (int j = 0; j < 8; ++j) {
    int e = e0 + t + j * 256;
    if (e < NE) {
      es[j] = src[e];
      ed[j] = dst[e];
      atomicAdd(&hist[ed[j] >> 9], 1);
    } else {
      es[j] = -1;
      ed[j] = 0;
    }
  }
  __syncthreads();
  sc[t] = (t < NBUK) ? hist[t] : 0;
  __syncthreads();
  for (int off = 1; off < 256; off <<= 1) {
    int v = (t >= off) ? sc[t - off] : 0;
    __syncthreads();
    sc[t] += v;
    __syncthreads();
  }
  if (t < NBUK) {
    int h = hist[t];
    int lb = sc[t] - h;
    lbase[t] = lb;
    lcur[t] = lb;
    if (h > 0) gbase[t] = atomicAdd(&bucket_cur[t], h);
  }
  __syncthreads();
#pragma unroll
  for (int j = 0; j < 8; ++j) {
    if (es[j] >= 0) {
      int b = ed[j] >> 9;
      int slot = atomicAdd(&lcur[b], 1);
      stage[slot] = make_uint2((unsigned)es[j], (unsigned)ed[j]);
    }
  }
  __syncthreads();
  int total = min(EPB, NE - e0);
  for (int i = t; i < total; i += 256) {
    uint2 p = stage[i];
    int b = (int)(p.y >> 9);
    binned[(size_t)gbase[b] + (i - lbase[b])] = (p.x << 9) | (p.y & 511u);
  }
}

// scan bucket fill counts -> global bucket bases
__global__ __launch_bounds__(256) void bucket_scan(const int* __restrict__ bucket_cur,
                                                   int* __restrict__ bucket_base,
                                                   int* __restrict__ row_ptr) {
  __shared__ int part[256];
  int t = threadIdx.x;
  int v = (t < NBUK) ? (bucket_cur[t] - t * BCAP) : 0;
  part[t] = v;
  __syncthreads();
  for (int off = 1; off < 256; off <<= 1) {
    int u = (t >= off) ? part[t - off] : 0;
    __syncthreads();
    part[t] += u;
    __syncthreads();
  }
  if (t < NBUK) bucket_base[t] = part[t] - v;
  if (t == 0) row_ptr[NN] = NE;
}

// pass B: per bucket — per-node histogram + scan in LDS, write row_ptr/deg_inv/col coalesced
__global__ __launch_bounds__(256) void binB(const unsigned* __restrict__ binned,
                                            const int* __restrict__ bucket_cur,
                                            const int* __restrict__ bucket_base,
                                            int* __restrict__ row_ptr,
                                            float* __restrict__ deg_inv,
                                            int* __restrict__ col) {
  __shared__ int hist[NPB];
  __shared__ int cur2[NPB];
  __shared__ int part[256];
  __shared__ int srcS[BCAP];
  int b = blockIdx.x;
  int n0 = b * NPB;
  int n1 = min(n0 + NPB, NN);
  int cnt = bucket_cur[b] - b * BCAP;
  int gb = bucket_base[b];
  size_t seg = (size_t)b * BCAP;
  int t = threadIdx.x;
  hist[t] = 0;
  hist[t + 256] = 0;
  __syncthreads();
  for (int i = t; i < cnt; i += 256)
    atomicAdd(&hist[(int)(binned[seg + i] & 511u)], 1);
  __syncthreads();
  int c0 = hist[2 * t], c1 = hist[2 * t + 1];
  int s = c0 + c1;
  part[t] = s;
  __syncthreads();
  for (int off = 1; off < 256; off <<= 1) {
    int u = (t >= off) ? part[t - off] : 0;
    __syncthreads();
    part[t] += u;
    __syncthreads();
  }
  int excl = part[t] - s;
  cur2[2 * t] = excl;
  cur2[2 * t + 1] = excl + c0;
  int n = n0 + 2 * t;
  if (n < n1) {
    row_ptr[n] = gb + excl;
    deg_inv[n] = 1.0f / (float)(c0 > 1 ? c0 : 1);
  }
  if (n + 1 < n1) {
    row_ptr[n + 1] = gb + excl + c0;
    deg_inv[n + 1] = 1.0f / (float)(c1 > 1 ? c1 : 1);
  }
  __syncthreads();
  for (int i = t; i < cnt; i += 256) {
    unsigned p = binned[seg + i];
    int slot = atomicAdd(&cur2[(int)(p & 511u)], 1);
    srcS[slot] = (int)(p >> 9);
  }
  __syncthreads();
  for (int i = t; i < cnt; i += 256) col[(size_t)gb + i] = srcS[i];
}

// ---------------- x -> fp16 shadow ----------------

__global__ __launch_bounds__(256) void tohalf(const float* __restrict__ x,
                                              __half* __restrict__ x16) {
  size_t o = ((size_t)blockIdx.x * 256 + threadIdx.x) * 8;
  float4 a = *(const float4*)(x + o);
  float4 b = *(const float4*)(x + o + 4);
  union { uint4 u; __half h[8]; } U;
  U.h[0] = __float2half(a.x); U.h[1] = __float2half(a.y);
  U.h[2] = __float2half(a.z); U.h[3] = __float2half(a.w);
  U.h[4] = __float2half(b.x); U.h[5] = __float2half(b.y);
  U.h[6] = __float2half(b.z); U.h[7] = __float2half(b.w);
  *(uint4*)(x16 + o) = U.u;
}

// ---------------- weight prep: fp16 transposed B operands ----------------

__global__ __launch_bounds__(256) void prep_weights(const float* __restrict__ Wl,
                                                    const float* __restrict__ Wr,
                                                    const float* __restrict__ Wp,
                                                    _Float16* __restrict__ WcatT,
                                                    _Float16* __restrict__ WpT) {
  int t = blockIdx.x * 256 + threadIdx.x;
  if (t < 4 * 64 * 128) {
    int l = t >> 13, rem = t & 8191, j = rem >> 7, k = rem & 127;
    float v = (k < 64) ? Wl[l * 4096 + k * 64 + j] : Wr[l * 4096 + (k - 64) * 64 + j];
    WcatT[t] = (_Float16)v;
  }
  if (t < 4 * 32 * 64) {
    int l = t >> 11, rem = t & 2047, j = rem >> 6, k = rem & 63;
    WpT[t] = (_Float16)Wp[(size_t)(l * 64 + k) * 32 + j];
  }
}

// ---------------- fused layer: paired-node gather (LDS) + MFMA GEMM + projection ----------------
// 64 nodes / 256-thread block (4 waves), 16 nodes per wave, processed as 8 PAIRS.
// Gather: lane l handles row-class r4=l>>4, feature quad fq=4*(l&15) (uint2 loads);
// per pair, 4-edge groups of nodes A and B are interleaved 2-deep -> 4 loads in flight
// before any accumulate. Per-lane validity predication replaces main/tail loops.
// Epilogue: two independent shfl_xor(16,32) folds; lanes 0-15 write row A, 16-31 row B.
// Cold path (deg>64, absent on this input): broadcast loop, r4==0 accumulates.
// MFMA phase as round 12. flags bit0: layer0 (init out with bp); bit1: write hn16.

#define PADA 72  // row stride (halves): 144B rows, 16B-aligned
#define PADC 72

#define ACC4(acc, v)                                        \
  {                                                         \
    float2 _a = __half22float2(*(__half2*)&(v).x);          \
    float2 _b = __half22float2(*(__half2*)&(v).y);          \
    (acc)[0] += _a.x; (acc)[1] += _a.y;                     \
    (acc)[2] += _b.x; (acc)[3] += _b.y;                     \
  }

__global__ __launch_bounds__(256, 4) void fused_layer(
    const _Float16* __restrict__ h16,
    const int* __restrict__ row_ptr, const int* __restrict__ col,
    const float* __restrict__ deginv,
    const _Float16* __restrict__ WcatT, const float* __restrict__ bl,
    const _Float16* __restrict__ WpT, const float* __restrict__ bp,
    _Float16* __restrict__ hn16, float* __restrict__ out, int flags) {
  __shared__ _Float16 aggS[64 * PADA];
  __shared__ _Float16 cS[64 * PADC];
  int tid = threadIdx.x;
  int w = tid >> 6, l = tid & 63;
  int base = blockIdx.x * 64;
  int r4 = l >> 4;          // row-class within 4-edge group
  int fq = (l & 15) * 4;    // feature quad base

  // ---- phase 1: gather-mean over node pairs ----
  for (int i = 0; i < 8; ++i) {
    int nA = base + (w << 4) + 2 * i;
    int nB = nA + 1;
    int ia = min(nA, NN), ib = min(nB, NN), ic = min(nB + 1, NN);
    int begA = row_ptr[ia];
    int mid  = row_ptr[ib];
    int endB = row_ptr[ic];
    int chAt = mid - begA;   // 0 for OOB nodes (clamped indices collapse)
    int chBt = endB - mid;
    int chA = min(chAt, 64), chB = min(chBt, 64);
    f32x4 accA = (f32x4){0.f, 0.f, 0.f, 0.f};
    f32x4 accB = (f32x4){0.f, 0.f, 0.f, 0.f};
    int cvA = 0, cvB = 0;
    if (chA > 0) cvA = col[begA + (l < chA ? l : chA - 1)];
    if (chB > 0) cvB = col[mid + (l < chB ? l : chB - 1)];
    int gA = (chA + 3) >> 2, gB = (chB + 3) >> 2;
    int gm = gA > gB ? gA : gB;
    int g = 0;
    for (; g + 2 <= gm; g += 2) {
      bool fa0 = g < gA, fb0 = g < gB, fa1 = g + 1 < gA, fb1 = g + 1 < gB;
      int q0 = 4 * g + r4, q1 = q0 + 4;
      uint2 va0, vb0, va1, vb1;
      if (fa0) va0 = *(const uint2*)(h16 + (size_t)__shfl(cvA, q0 < chA ? q0 : chA - 1, 64) * 64 + fq);
      if (fb0) vb0 = *(const uint2*)(h16 + (size_t)__shfl(cvB, q0 < chB ? q0 : chB - 1, 64) * 64 + fq);
      if (fa1) va1 = *(const uint2*)(h16 + (size_t)__shfl(cvA, q1 < chA ? q1 : chA - 1, 64) * 64 + fq);
      if (fb1) vb1 = *(const uint2*)(h16 + (size_t)__shfl(cvB, q1 < chB ? q1 : chB - 1, 64) * 64 + fq);
      if (fa0 && q0 < chA) ACC4(accA, va0);
      if (fb0 && q0 < chB) ACC4(accB, vb0);
      if (fa1 && q1 < chA) ACC4(accA, va1);
      if (fb1 && q1 < chB) ACC4(accB, vb1);
    }
    if (g < gm) {
      bool fa = g < gA, fb = g < gB;
      int q0 = 4 * g + r4;
      uint2 va, vb;
      if (fa) va = *(const uint2*)(h16 + (size_t)__shfl(cvA, q0 < chA ? q0 : chA - 1, 64) * 64 + fq);
      if (fb) vb = *(const uint2*)(h16 + (size_t)__shfl(cvB, q0 < chB ? q0 : chB - 1, 64) * 64 + fq);
      if (fa && q0 < chA) ACC4(accA, va);
      if (fb && q0 < chB) ACC4(accB, vb);
    }
    // cold path: degrees > 64 (not present on this input)
    if (__builtin_expect(chAt > 64, 0)) {
      for (int e = begA + 64; e < mid; ++e) {
        uint2 v = *(const uint2*)(h16 + (size_t)col[e] * 64 + fq);
        if (r4 == 0) ACC4(accA, v);
      }
    }
    if (__builtin_expect(chBt > 64, 0)) {
      for (int e = mid + 64; e < endB; ++e) {
        uint2 v = *(const uint2*)(h16 + (size_t)col[e] * 64 + fq);
        if (r4 == 0) ACC4(accB, v);
      }
    }
    // fold 4 row-classes (two independent chains)
#pragma unroll
    for (int k = 0; k < 4; ++k) {
      accA[k] += __shfl_xor(accA[k], 16, 64);
      accB[k] += __shfl_xor(accB[k], 16, 64);
      accA[k] += __shfl_xor(accA[k], 32, 64);
      accB[k] += __shfl_xor(accB[k], 32, 64);
    }
    int rowA = (w << 4) + 2 * i;
    if (l < 16) {
      float di = (nA < NN) ? deginv[nA] : 0.f;
      union { uint2 u; __half2 h2[2]; } P;
      P.h2[0] = __floats2half2_rn(accA[0] * di, accA[1] * di);
      P.h2[1] = __floats2half2_rn(accA[2] * di, accA[3] * di);
      *(uint2*)(aggS + rowA * PADA + (l & 15) * 4) = P.u;
    } else if (l < 32) {
      float di = (nB < NN) ? deginv[nB] : 0.f;
      union { uint2 u; __half2 h2[2]; } P;
      P.h2[0] = __floats2half2_rn(accB[0] * di, accB[1] * di);
      P.h2[1] = __floats2half2_rn(accB[2] * di, accB[3] * di);
      *(uint2*)(aggS + (rowA + 1) * PADA + (l & 15) * 4) = P.u;
    }
  }
  __syncthreads();

  // ---- phase 2: MFMA GEMM (wave w owns rows w*16..w*16+15, all 4 col-tiles) ----
  int lr = l & 15, lg = l >> 4;
  int arow = base + (w << 4) + lr;

  f32x4 acc4[4];
#pragma unroll
  for (int ct = 0; ct < 4; ++ct) {
    float b = bl[ct * 16 + lr];
    acc4[ct] = (f32x4){b, b, b, b};
  }
  const half8 a0 = *(const half8*)(aggS + ((w << 4) + lr) * PADA + lg * 8);
  const half8 a1 = *(const half8*)(aggS + ((w << 4) + lr) * PADA + 32 + lg * 8);
  const half8 a2 = *(const half8*)(h16 + (size_t)arow * 64 + lg * 8);
  const half8 a3 = *(const half8*)(h16 + (size_t)arow * 64 + 32 + lg * 8);
#pragma unroll
  for (int ct = 0; ct < 4; ++ct) {
    const _Float16* wb = WcatT + (ct * 16 + lr) * 128 + lg * 8;
    half8 b0 = *(const half8*)(wb);
    half8 b1 = *(const half8*)(wb + 32);
    half8 b2 = *(const half8*)(wb + 64);
    half8 b3 = *(const half8*)(wb + 96);
    acc4[ct] = __builtin_amdgcn_mfma_f32_16x16x32_f16(a0, b0, acc4[ct], 0, 0, 0);
    acc4[ct] = __builtin_amdgcn_mfma_f32_16x16x32_f16(a1, b1, acc4[ct], 0, 0, 0);
    acc4[ct] = __builtin_amdgcn_mfma_f32_16x16x32_f16(a2, b2, acc4[ct], 0, 0, 0);
    acc4[ct] = __builtin_amdgcn_mfma_f32_16x16x32_f16(a3, b3, acc4[ct], 0, 0, 0);
  }

  // stage hn tile to LDS (fp16): D-layout scatter
#pragma unroll
  for (int ct = 0; ct < 4; ++ct)
#pragma unroll
    for (int r = 0; r < 4; ++r)
      cS[((w << 4) + (lg << 2) + r) * PADC + ct * 16 + lr] = (_Float16)acc4[ct][r];
  __syncthreads();

  // coalesced hn16 write from LDS (skipped on last layer)
  if (flags & 2) {
#pragma unroll
    for (int j = 0; j < 2; ++j) {
      int idx = tid + j * 256;
      int row = idx >> 3, c8 = (idx & 7) * 8;
      *(half8*)(hn16 + (size_t)(base + row) * 64 + c8) =
          *(const half8*)(cS + row * PADC + c8);
    }
  }

  // projection: out(64x32) (+)= C(64x64) @ Wp(64x32)
  f32x4 pacc[2];
#pragma unroll
  for (int pt = 0; pt < 2; ++pt) {
    int colo = pt * 16 + lr;
    if (flags & 1) {
      float b = bp[colo];
      pacc[pt] = (f32x4){b, b, b, b};
    } else {
#pragma unroll
      for (int r = 0; r < 4; ++r) {
        int row = base + (w << 4) + (lg << 2) + r;
        pacc[pt][r] = (row < NN) ? out[(size_t)row * 32 + colo] : 0.f;
      }
    }
  }
  const _Float16* crow = cS + ((w << 4) + lr) * PADC + lg * 8;
  half8 c0 = *(const half8*)(crow);
  half8 c1 = *(const half8*)(crow + 32);
#pragma unroll
  for (int pt = 0; pt < 2; ++pt) {
    const _Float16* wp = WpT + (pt * 16 + lr) * 64 + lg * 8;
    half8 w0 = *(const half8*)(wp);
    half8 w1 = *(const half8*)(wp + 32);
    pacc[pt] = __builtin_amdgcn_mfma_f32_16x16x32_f16(c0, w0, pacc[pt], 0, 0, 0);
    pacc[pt] = __builtin_amdgcn_mfma_f32_16x16x32_f16(c1, w1, pacc[pt], 0, 0, 0);
  }
#pragma unroll
  for (int pt = 0; pt < 2; ++pt) {
    int colo = pt * 16 + lr;
#pragma unroll
    for (int r = 0; r < 4; ++r) {
      int row = base + (w << 4) + (lg << 2) + r;
      if (row < NN) out[(size_t)row * 32 + colo] = pacc[pt][r];
    }
  }
}

// ---------------- launch ----------------

extern "C" void kernel_launch(void* const* d_in, const int* in_sizes, int n_in,
                              void* d_out, int out_size, void* d_ws, size_t ws_size,
                              hipStream_t stream) {
  const float* x  = (const float*)d_in[0];
  const int*   ei = (const int*)d_in[1];   // [2, NE] int32
  const float* Wl = (const float*)d_in[2];
  const float* bl = (const float*)d_in[3];
  const float* Wr = (const float*)d_in[4];
  const float* Wp = (const float*)d_in[5];
  const float* bp = (const float*)d_in[6];
  float* out = (float*)d_out;

  char* ws = (char*)d_ws;
  size_t off = 0;
  auto alloc = [&](size_t bytes) {
    void* p = ws + off;
    off = (off + bytes + 255) & ~(size_t)255;
    return p;
  };
  int*      row_ptr     = (int*)alloc(((size_t)NN + 1) * 4);
  float*    deginv      = (float*)alloc((size_t)NN * 4);
  int*      col         = (int*)alloc((size_t)NE * 4);
  int*      bucket_cur  = (int*)alloc((size_t)NBUK * 4);
  int*      bucket_base = (int*)alloc((size_t)NBUK * 4);
  unsigned* binned      = (unsigned*)alloc((size_t)NBUK * BCAP * 4);
  __half*   x16         = (__half*)alloc((size_t)NNP * 64 * 2);
  __half*   h16A        = (__half*)alloc((size_t)NNP * 64 * 2);
  __half*   h16B        = (__half*)alloc((size_t)NNP * 64 * 2);
  _Float16* WcatT       = (_Float16*)alloc((size_t)4 * 64 * 128 * 2);
  _Float16* WpT         = (_Float16*)alloc((size_t)4 * 32 * 64 * 2);

  tohalf<<<3125, 256, 0, stream>>>(x, x16);
  prep_weights<<<128, 256, 0, stream>>>(Wl, Wr, Wp, WcatT, WpT);
  bucket_init<<<1, 256, 0, stream>>>(bucket_cur);
  binA<<<ABLK, 256, 0, stream>>>(ei, ei + NE, bucket_cur, binned);
  bucket_scan<<<1, 256, 0, stream>>>(bucket_cur, bucket_base, row_ptr);
  binB<<<NBUK, 256, 0, stream>>>(binned, bucket_cur, bucket_base, row_ptr, deginv, col);

  const __half* cur16 = x16;
  __half* bufs[2] = {h16A, h16B};
  int nblk = (NN + 63) / 64;  // 1563
  for (int l = 0; l < 4; ++l) {
    __half* nxt = bufs[l & 1];
    int flags = (l == 0 ? 1 : 0) | (l < 3 ? 2 : 0);
    fused_layer<<<nblk, 256, 0, stream>>>(
        (const _Float16*)cur16, row_ptr, col, deginv,
        WcatT + l * 8192, bl + l * 64, WpT + l * 2048, bp,
        (_Float16*)nxt, out, flags);
    cur16 = nxt;
  }
}